// Round 9
// baseline (129.147 us; speedup 1.0000x reference)
//
#include <hip/hip_runtime.h>
#include <hip/hip_bf16.h>
#include <cstdint>
#include <cstddef>

#define BATCH 8
#define CINC  64
#define HH    128
#define WWW   128
#define COUTC 128
#define KKC   9
#define KDIM  576   // KK*CIN, k = kk*64 + c
#define HWC   (HH*WWW)      // 16384
#define NPX   (BATCH*HWC)   // 131072

#define AT_BASE 98304       // window = 6*128*128
#define AT_SZ   32768       // one A-tile buffer (256 px * 128 B)

typedef float f32x4 __attribute__((ext_vector_type(4)));
typedef short bf16x8 __attribute__((ext_vector_type(8)));

static __device__ __forceinline__ unsigned short f2bf(float f){
    unsigned u = __builtin_bit_cast(unsigned, f);
    u += 0x7fffu + ((u >> 16) & 1u);
    return (unsigned short)(u >> 16);
}
static __device__ __forceinline__ float bf_lo(unsigned u){
    return __builtin_bit_cast(float, u << 16);
}
static __device__ __forceinline__ float bf_hi(unsigned u){
    return __builtin_bit_cast(float, u & 0xffff0000u);
}
static __device__ __forceinline__ unsigned cvtpk(float lo, float hi){
    unsigned r;
    asm("v_cvt_pk_bf16_f32 %0, %1, %2" : "=v"(r) : "v"(lo), "v"(hi));
    return r;
}

// ---------------- K0: pack weights to bf16 ---------------------------------
__global__ __launch_bounds__(256) void prep_weights(
        const float* __restrict__ off_w, const float* __restrict__ mod_w,
        const float* __restrict__ reg_w, const float* __restrict__ pre_w,
        unsigned short* __restrict__ Wb, unsigned short* __restrict__ Wc,
        unsigned short* __restrict__ Wp)
{
    int idx = blockIdx.x * 256 + threadIdx.x;
    if (idx < COUTC * KDIM) {
        int o = idx / KDIM, k = idx % KDIM;
        int kk = k >> 6, c = k & 63;
        Wb[idx] = f2bf(reg_w[(o * CINC + c) * KKC + kk]);
    }
    int idx2 = idx - COUTC * KDIM;
    if (idx2 >= 0 && idx2 < 32 * KDIM) {
        int o = idx2 / KDIM, k = idx2 % KDIM;
        int kk = k >> 6, c = k & 63;
        float v = 0.f;
        if (o < 18)      v = off_w[(o * CINC + c) * KKC + kk];
        else if (o < 27) v = mod_w[((o - 18) * CINC + c) * KKC + kk];
        Wc[idx2] = f2bf(v);
    }
    int idx3 = idx - (COUTC * KDIM + 32 * KDIM);
    if (idx3 >= 0 && idx3 < CINC * CINC)
        Wp[idx3] = f2bf(pre_w[idx3]);
}

// ---------------- K1: 1x1 conv via MFMA, NCHW f32 -> NHWC bf16 --------------
__global__ __launch_bounds__(256) void conv1x1(
        const float* __restrict__ x, const unsigned short* __restrict__ Wp,
        const float* __restrict__ pre_b, unsigned short* __restrict__ xp)
{
    __shared__ unsigned short slab[4][64 * 72];

    const int tid = threadIdx.x;
    const int lane = tid & 63;
    const int wv   = tid >> 6;
    const int l15  = lane & 15;
    const int l4   = lane >> 4;

    int bid = (int)blockIdx.x;
    int bswz = (bid & 7) * 64 + (bid >> 3);
    int pxb = bswz * 256 + wv * 64;
    int b = pxb >> 14, hw0 = pxb & 16383;
    const float* xb = x + (size_t)b * CINC * HWC + hw0;

    bf16x8 bw[4][2];
    #pragma unroll
    for (int fn = 0; fn < 4; ++fn)
        #pragma unroll
        for (int s = 0; s < 2; ++s)
            bw[fn][s] = *(const bf16x8*)(Wp + (size_t)(16*fn + l15) * 64 + 32*s + 8*l4);
    float pb[4];
    #pragma unroll
    for (int fn = 0; fn < 4; ++fn) pb[fn] = pre_b[16*fn + l15];

    f32x4 acc[4][4];
    #pragma unroll
    for (int su = 0; su < 4; ++su)
        #pragma unroll
        for (int fn = 0; fn < 4; ++fn) acc[su][fn] = (f32x4){0.f,0.f,0.f,0.f};

    #pragma unroll
    for (int su = 0; su < 4; ++su) {
        #pragma unroll
        for (int s = 0; s < 2; ++s) {
            float f[8];
            #pragma unroll
            for (int j = 0; j < 8; ++j)
                f[j] = xb[(size_t)(s*32 + 8*l4 + j) * HWC + su*16 + l15];
            unsigned pk[4];
            #pragma unroll
            for (int d = 0; d < 4; ++d) pk[d] = cvtpk(f[2*d], f[2*d+1]);
            bf16x8 A = __builtin_bit_cast(bf16x8, make_uint4(pk[0], pk[1], pk[2], pk[3]));
            #pragma unroll
            for (int fn = 0; fn < 4; ++fn)
                acc[su][fn] = __builtin_amdgcn_mfma_f32_16x16x32_bf16(A, bw[fn][s], acc[su][fn], 0,0,0);
        }
    }

    unsigned short* sl = slab[wv];
    #pragma unroll
    for (int su = 0; su < 4; ++su)
        #pragma unroll
        for (int fn = 0; fn < 4; ++fn)
            #pragma unroll
            for (int r = 0; r < 4; ++r)
                sl[(su*16 + 4*l4 + r) * 72 + 16*fn + l15] = f2bf(acc[su][fn][r] + pb[fn]);
    const uint4* srow = (const uint4*)(sl + lane * 72);
    uint4* drow = (uint4*)(xp + (size_t)(pxb + lane) * 64);
    #pragma unroll
    for (int q = 0; q < 8; ++q) drow[q] = srow[q];
}

// ---------------- K3: fused, producer/consumer wave-specialized -------------
// 512 blocks x 512 thr. Block = 2 rows (256 px). LDS = 160 KiB exactly:
// window 6x128 px x 128B (XOR-swizzled) + 2 x 32 KB A-tile double buffer.
// Waves 0-3 = producers (lerp 64 px/kk -> At[kk&1]); waves 4-7 = consumers
// (32 couts each, acc[16][2] AGPRs, GEMM on At[(kk-1)&1]). One barrier/kk:
// producer(kk) overlaps consumer(kk-1) => VALU || MFMA+LDS continuously.
// Coords: phase-O -> Dt(LDS) -> gco(global, L2-hot) -> producers re-read/kk.
__global__ __launch_bounds__(512, 2) void gather_einsum(
        const unsigned short* __restrict__ xp,
        const unsigned short* __restrict__ Wb,
        const unsigned short* __restrict__ Wc,
        const float* __restrict__ off_b,
        const float* __restrict__ mod_b,
        float* __restrict__ gco,
        float* __restrict__ out)
{
    __shared__ char smem[163840];
    char* winc = smem;                       // [6][128] px, 128B, swizzled
    float* epi = (float*)smem;               // epilogue [128][260] f32

    const int tid  = (int)threadIdx.x;
    const int lane = tid & 63;
    const int wv   = tid >> 6;       // 0..7
    const int l15  = lane & 15;
    const int l4   = lane >> 4;

    int bid = (int)blockIdx.x;
    int bswz = (bid & 7) * 64 + (bid >> 3);
    const int b  = bswz >> 6;
    const int h0 = (bswz & 63) * 2;

    const unsigned short* xpb = xp + (size_t)b * HWC * CINC;
    float* gcb = gco + (size_t)bid * 6912;   // [27][256] f32 per block

    // ---- stage window rows h0-2..h0+3, swizzled ----
    #pragma unroll
    for (int i = 0; i < 12; ++i) {
        int c = i * 512 + tid;            // 0..6143
        int r = c >> 10;
        int c10 = c & 1023;
        int xph = c10 >> 3, g = c10 & 7;
        int y = h0 - 2 + r;
        uint4 v = make_uint4(0u,0u,0u,0u);
        if ((unsigned)y < 128u)
            v = *(const uint4*)(xpb + ((size_t)y * 128 + xph) * 64 + g * 8);
        *(uint4*)(winc + (r*128 + xph)*128 + ((g ^ (xph & 7)) << 4)) = v;
    }
    __syncthreads();

    // ---- Phase O: offset/mask conv (all 8 waves, 32 px each) ----
    {
        const int hrow = wv >> 2;
        const int x0w  = (wv & 3) * 32;
        f32x4 aco[2][2];
        #pragma unroll
        for (int j = 0; j < 2; ++j)
            #pragma unroll
            for (int fn = 0; fn < 2; ++fn) aco[j][fn] = (f32x4){0.f,0.f,0.f,0.f};

        #pragma unroll
        for (int kk = 0; kk < 9; ++kk) {
            bf16x8 bc0[2], bc1[2];
            #pragma unroll
            for (int fn = 0; fn < 2; ++fn) {
                bc0[fn] = *(const bf16x8*)(Wc + (size_t)(16*fn + l15) * KDIM + kk*64 + 8*l4);
                bc1[fn] = *(const bf16x8*)(Wc + (size_t)(16*fn + l15) * KDIM + kk*64 + 32 + 8*l4);
            }
            int wr_ = hrow + (kk / 3) + 1;
            #pragma unroll
            for (int j = 0; j < 2; ++j) {
                int xx = x0w + j*16 + l15 + (kk % 3) - 1;
                bool xv = (unsigned)xx < 128u;
                int xc = xx < 0 ? 0 : (xx > 127 ? 127 : xx);
                int sx = xc & 7;
                const char* rr = winc + (wr_*128 + xc)*128;
                uint4 a0 = *(const uint4*)(rr + ((l4 ^ sx) << 4));
                uint4 a1 = *(const uint4*)(rr + (((l4+4) ^ sx) << 4));
                if (!xv) { a0 = make_uint4(0,0,0,0); a1 = make_uint4(0,0,0,0); }
                bf16x8 A0 = __builtin_bit_cast(bf16x8, a0);
                bf16x8 A1 = __builtin_bit_cast(bf16x8, a1);
                #pragma unroll
                for (int fn = 0; fn < 2; ++fn) {
                    aco[j][fn] = __builtin_amdgcn_mfma_f32_16x16x32_bf16(A0, bc0[fn], aco[j][fn], 0,0,0);
                    aco[j][fn] = __builtin_amdgcn_mfma_f32_16x16x32_bf16(A1, bc1[fn], aco[j][fn], 0,0,0);
                }
            }
        }
        // D -> Dt[px][o] (pitch 29 f32) in At area
        float* Dt = (float*)(smem + AT_BASE);
        #pragma unroll
        for (int j = 0; j < 2; ++j)
        #pragma unroll
        for (int fn = 0; fn < 2; ++fn) {
            int o = 16*fn + l15;
            #pragma unroll
            for (int r = 0; r < 4; ++r) {
                int pr = 4*l4 + r;
                int px = wv*32 + j*16 + pr;
                float v = aco[j][fn][r];
                if (o < 18) {
                    v += off_b[o];
                    int k = o >> 1;
                    if ((o & 1) == 0) v += (float)(h0 + hrow - 1 + k/3);
                    else              v += (float)(x0w + j*16 + pr - 1 + (k % 3));
                } else if (o < 27) {
                    v = 2.f / (1.f + __expf(-(v + mod_b[o - 18])));
                }
                if (o < 27) Dt[px*29 + o] = v;
            }
        }
    }
    __syncthreads();

    // ---- Dt -> gco (coalesced), layout gco[o*256 + px] ----
    {
        const float* Dt = (const float*)(smem + AT_BASE);
        for (int i = tid; i < 6912; i += 512) {
            int o = i >> 8, p = i & 255;
            gcb[i] = Dt[p*29 + o];
        }
    }
    __syncthreads();   // gco visible; Dt area free for At buffers

    // ---- roles ----
    const int pw = wv;           // producer id 0..3 (wv<4): px band 64*pw
    const int cw = wv - 4;       // consumer id 0..3 (wv>=4): couts 32*cw
    const unsigned short* wrow = Wb + (size_t)(32*cw + l15) * KDIM + 8*l4;

    f32x4 acc[16][2];
    #pragma unroll
    for (int m = 0; m < 16; ++m) { acc[m][0] = (f32x4){0.f,0.f,0.f,0.f};
                                   acc[m][1] = (f32x4){0.f,0.f,0.f,0.f}; }

    auto lerp_tile = [&](int kk, char* Ab) {
        #pragma unroll
        for (int js = 0; js < 4; ++js) {
            int pxl = pw*64 + js*16 + l15;
            float Y = gcb[(2*kk  )*256 + pxl];
            float X = gcb[(2*kk+1)*256 + pxl];
            float M = gcb[(18+kk )*256 + pxl];
            float yf = floorf(Y), xf = floorf(X);
            float wy = Y - yf, wx = X - xf;
            int y0 = (int)yf, x0i = (int)xf;
            int y1 = y0 + 1, x1 = x0i + 1;
            bool yv0 = (unsigned)y0 < 128u, yv1 = (unsigned)y1 < 128u;
            bool xv0 = (unsigned)x0i < 128u, xv1 = (unsigned)x1 < 128u;
            int xc0 = x0i < 0 ? 0 : (x0i > 127 ? 127 : x0i);
            int xc1 = x1  < 0 ? 0 : (x1  > 127 ? 127 : x1);
            int wr0 = y0 - (h0 - 2), wr1 = wr0 + 1;
            int wc0 = wr0 < 0 ? 0 : (wr0 > 5 ? 5 : wr0);
            int wc1 = wr1 < 0 ? 0 : (wr1 > 5 ? 5 : wr1);
            int s0 = xc0 & 7, s1 = xc1 & 7;

            const char* r00 = winc + (wc0*128 + xc0)*128;
            const char* r01 = winc + (wc0*128 + xc1)*128;
            const char* r10 = winc + (wc1*128 + xc0)*128;
            const char* r11 = winc + (wc1*128 + xc1)*128;
            uint4 cb0 = *(const uint4*)(r00 + ((l4 ^ s0) << 4));
            uint4 cb1 = *(const uint4*)(r00 + (((l4+4) ^ s0) << 4));
            uint4 cb2 = *(const uint4*)(r01 + ((l4 ^ s1) << 4));
            uint4 cb3 = *(const uint4*)(r01 + (((l4+4) ^ s1) << 4));
            uint4 cb4 = *(const uint4*)(r10 + ((l4 ^ s0) << 4));
            uint4 cb5 = *(const uint4*)(r10 + (((l4+4) ^ s0) << 4));
            uint4 cb6 = *(const uint4*)(r11 + ((l4 ^ s1) << 4));
            uint4 cb7 = *(const uint4*)(r11 + (((l4+4) ^ s1) << 4));

            bool oob = (yv0 && (unsigned)wr0 > 5u) || (yv1 && (unsigned)wr1 > 5u);
            if (__builtin_expect(oob, 0)) {
                int yc0 = y0 < 0 ? 0 : (y0 > 127 ? 127 : y0);
                int yc1 = y1 < 0 ? 0 : (y1 > 127 ? 127 : y1);
                const unsigned short* p00 = xpb + (size_t)(yc0*128 + xc0)*64 + 8*l4;
                const unsigned short* p01 = xpb + (size_t)(yc0*128 + xc1)*64 + 8*l4;
                const unsigned short* p10 = xpb + (size_t)(yc1*128 + xc0)*64 + 8*l4;
                const unsigned short* p11 = xpb + (size_t)(yc1*128 + xc1)*64 + 8*l4;
                cb0 = *(const uint4*)(p00);  cb1 = *(const uint4*)(p00 + 32);
                cb2 = *(const uint4*)(p01);  cb3 = *(const uint4*)(p01 + 32);
                cb4 = *(const uint4*)(p10);  cb5 = *(const uint4*)(p10 + 32);
                cb6 = *(const uint4*)(p11);  cb7 = *(const uint4*)(p11 + 32);
            }

            float u00 = (1.f - wy) * (1.f - wx) * M * ((yv0 && xv0) ? 1.f : 0.f);
            float u01 = (1.f - wy) * wx         * M * ((yv0 && xv1) ? 1.f : 0.f);
            float u10 = wy * (1.f - wx)         * M * ((yv1 && xv0) ? 1.f : 0.f);
            float u11 = wy * wx                 * M * ((yv1 && xv1) ? 1.f : 0.f);

            unsigned pk0[4], pk1[4];
            #pragma unroll
            for (int d = 0; d < 4; ++d) {
                unsigned q00, q01, q10, q11;
                q00 = cb0[d]; q01 = cb2[d]; q10 = cb4[d]; q11 = cb6[d];
                {
                    float slo = bf_lo(q00)*u00 + bf_lo(q01)*u01 + bf_lo(q10)*u10 + bf_lo(q11)*u11;
                    float shi = bf_hi(q00)*u00 + bf_hi(q01)*u01 + bf_hi(q10)*u10 + bf_hi(q11)*u11;
                    pk0[d] = cvtpk(slo, shi);
                }
                q00 = cb1[d]; q01 = cb3[d]; q10 = cb5[d]; q11 = cb7[d];
                {
                    float slo = bf_lo(q00)*u00 + bf_lo(q01)*u01 + bf_lo(q10)*u10 + bf_lo(q11)*u11;
                    float shi = bf_hi(q00)*u00 + bf_hi(q01)*u01 + bf_hi(q10)*u10 + bf_hi(q11)*u11;
                    pk1[d] = cvtpk(slo, shi);
                }
            }
            int sw = l15 & 7;
            char* ab = Ab + pxl*128;
            *(uint4*)(ab + ((l4 ^ sw) << 4))     = make_uint4(pk0[0], pk0[1], pk0[2], pk0[3]);
            *(uint4*)(ab + (((l4+4) ^ sw) << 4)) = make_uint4(pk1[0], pk1[1], pk1[2], pk1[3]);
        }
    };

    auto gemm_step = [&](int g) {
        const char* Ab = smem + AT_BASE + (g & 1) * AT_SZ;
        bf16x8 Bf00 = *(const bf16x8*)(wrow + g*64);
        bf16x8 Bf01 = *(const bf16x8*)(wrow + g*64 + 32);
        bf16x8 Bf10 = *(const bf16x8*)(wrow + (size_t)16*KDIM + g*64);
        bf16x8 Bf11 = *(const bf16x8*)(wrow + (size_t)16*KDIM + g*64 + 32);
        int sw = l15 & 7;
        int o1 = (l4 ^ sw) << 4, o2 = ((l4 + 4) ^ sw) << 4;
        #pragma unroll
        for (int m = 0; m < 16; ++m) {
            const char* ar = Ab + (16*m + l15)*128;
            bf16x8 A0 = *(const bf16x8*)(ar + o1);
            bf16x8 A1 = *(const bf16x8*)(ar + o2);
            acc[m][0] = __builtin_amdgcn_mfma_f32_16x16x32_bf16(A0, Bf00, acc[m][0], 0,0,0);
            acc[m][0] = __builtin_amdgcn_mfma_f32_16x16x32_bf16(A1, Bf01, acc[m][0], 0,0,0);
            acc[m][1] = __builtin_amdgcn_mfma_f32_16x16x32_bf16(A0, Bf10, acc[m][1], 0,0,0);
            acc[m][1] = __builtin_amdgcn_mfma_f32_16x16x32_bf16(A1, Bf11, acc[m][1], 0,0,0);
        }
    };

    // ---- software-pipelined main loop: producer(kk) || consumer(kk-1) ----
    #pragma unroll 1
    for (int step = 0; step <= 9; ++step) {
        if (step <= 8 && wv < 4)
            lerp_tile(step, smem + AT_BASE + (step & 1) * AT_SZ);
        if (step >= 1 && wv >= 4)
            gemm_step(step - 1);
        __syncthreads();
    }

    // ---- epilogue: consumers -> epi [co][px pitch 260] -> full-line stores
    if (wv >= 4) {
        #pragma unroll
        for (int m = 0; m < 16; ++m)
            #pragma unroll
            for (int f = 0; f < 2; ++f)
                *(f32x4*)(epi + (size_t)(32*cw + 16*f + l15) * 260 + 16*m + 4*l4) = acc[m][f];
    }
    __syncthreads();

    float* ob = out + (size_t)b * COUTC * HWC + h0 * 128;
    #pragma unroll
    for (int it = 0; it < 16; ++it) {
        int idx = it * 512 + tid;
        int o = idx >> 6, c = idx & 63;
        f32x4 v = *(const f32x4*)(epi + (size_t)o * 260 + 4*c);
        *(f32x4*)(ob + (size_t)o * HWC + 4*c) = v;
    }
}

extern "C" void kernel_launch(void* const* d_in, const int* in_sizes, int n_in,
                              void* d_out, int out_size, void* d_ws, size_t ws_size,
                              hipStream_t stream)
{
    const float* x     = (const float*)d_in[0];
    const float* pre_w = (const float*)d_in[1];
    const float* pre_b = (const float*)d_in[2];
    const float* off_w = (const float*)d_in[3];
    const float* off_b = (const float*)d_in[4];
    const float* mod_w = (const float*)d_in[5];
    const float* mod_b = (const float*)d_in[6];
    const float* reg_w = (const float*)d_in[7];
    float* out = (float*)d_out;

    unsigned short* xp = (unsigned short*)d_ws;                              // 16,777,216 B
    unsigned short* Wb = (unsigned short*)((char*)d_ws + 16777216);          //    147,456 B
    unsigned short* Wc = (unsigned short*)((char*)d_ws + 16924672);          //     36,864 B
    unsigned short* Wp = (unsigned short*)((char*)d_ws + 16961536);          //      8,192 B
    float* gco = (float*)((char*)d_ws + 16969728);                           // 14,155,776 B

    prep_weights<<<dim3(376), dim3(256), 0, stream>>>(off_w, mod_w, reg_w, pre_w, Wb, Wc, Wp);
    conv1x1     <<<dim3(512), dim3(256), 0, stream>>>(x, Wp, pre_b, xp);
    gather_einsum<<<dim3(512), dim3(512), 0, stream>>>(xp, Wb, Wc, off_b, mod_b, gco, out);
}

// Round 10
// 103.944 us; speedup vs baseline: 1.2425x; 1.2425x over previous
//
#include <hip/hip_runtime.h>
#include <hip/hip_bf16.h>
#include <cstdint>
#include <cstddef>

#define BATCH 8
#define CINC  64
#define HH    128
#define WWW   128
#define COUTC 128
#define KKC   9
#define KDIM  576   // KK*CIN, k = kk*64 + c
#define HWC   (HH*WWW)      // 16384
#define NPX   (BATCH*HWC)   // 131072

#define AT_BASE 98304       // window = 6*128*128
#define AT_SZ   32768       // one A-tile buffer (256 px * 128 B)

typedef float f32x4 __attribute__((ext_vector_type(4)));
typedef short bf16x8 __attribute__((ext_vector_type(8)));

static __device__ __forceinline__ unsigned short f2bf(float f){
    unsigned u = __builtin_bit_cast(unsigned, f);
    u += 0x7fffu + ((u >> 16) & 1u);
    return (unsigned short)(u >> 16);
}
static __device__ __forceinline__ float bf_lo(unsigned u){
    return __builtin_bit_cast(float, u << 16);
}
static __device__ __forceinline__ float bf_hi(unsigned u){
    return __builtin_bit_cast(float, u & 0xffff0000u);
}
static __device__ __forceinline__ unsigned cvtpk(float lo, float hi){
    unsigned r;
    asm("v_cvt_pk_bf16_f32 %0, %1, %2" : "=v"(r) : "v"(lo), "v"(hi));
    return r;
}

// ---------------- K0: pack weights to bf16 ---------------------------------
__global__ __launch_bounds__(256) void prep_weights(
        const float* __restrict__ off_w, const float* __restrict__ mod_w,
        const float* __restrict__ reg_w, const float* __restrict__ pre_w,
        unsigned short* __restrict__ Wb, unsigned short* __restrict__ Wc,
        unsigned short* __restrict__ Wp)
{
    int idx = blockIdx.x * 256 + threadIdx.x;
    if (idx < COUTC * KDIM) {
        int o = idx / KDIM, k = idx % KDIM;
        int kk = k >> 6, c = k & 63;
        Wb[idx] = f2bf(reg_w[(o * CINC + c) * KKC + kk]);
    }
    int idx2 = idx - COUTC * KDIM;
    if (idx2 >= 0 && idx2 < 32 * KDIM) {
        int o = idx2 / KDIM, k = idx2 % KDIM;
        int kk = k >> 6, c = k & 63;
        float v = 0.f;
        if (o < 18)      v = off_w[(o * CINC + c) * KKC + kk];
        else if (o < 27) v = mod_w[((o - 18) * CINC + c) * KKC + kk];
        Wc[idx2] = f2bf(v);
    }
    int idx3 = idx - (COUTC * KDIM + 32 * KDIM);
    if (idx3 >= 0 && idx3 < CINC * CINC)
        Wp[idx3] = f2bf(pre_w[idx3]);
}

// ---------------- K1: 1x1 conv via MFMA, NCHW f32 -> NHWC bf16 --------------
__global__ __launch_bounds__(256) void conv1x1(
        const float* __restrict__ x, const unsigned short* __restrict__ Wp,
        const float* __restrict__ pre_b, unsigned short* __restrict__ xp)
{
    __shared__ unsigned short slab[4][64 * 72];

    const int tid = threadIdx.x;
    const int lane = tid & 63;
    const int wv   = tid >> 6;
    const int l15  = lane & 15;
    const int l4   = lane >> 4;

    int bid = (int)blockIdx.x;
    int bswz = (bid & 7) * 64 + (bid >> 3);
    int pxb = bswz * 256 + wv * 64;
    int b = pxb >> 14, hw0 = pxb & 16383;
    const float* xb = x + (size_t)b * CINC * HWC + hw0;

    bf16x8 bw[4][2];
    #pragma unroll
    for (int fn = 0; fn < 4; ++fn)
        #pragma unroll
        for (int s = 0; s < 2; ++s)
            bw[fn][s] = *(const bf16x8*)(Wp + (size_t)(16*fn + l15) * 64 + 32*s + 8*l4);
    float pb[4];
    #pragma unroll
    for (int fn = 0; fn < 4; ++fn) pb[fn] = pre_b[16*fn + l15];

    f32x4 acc[4][4];
    #pragma unroll
    for (int su = 0; su < 4; ++su)
        #pragma unroll
        for (int fn = 0; fn < 4; ++fn) acc[su][fn] = (f32x4){0.f,0.f,0.f,0.f};

    #pragma unroll
    for (int su = 0; su < 4; ++su) {
        #pragma unroll
        for (int s = 0; s < 2; ++s) {
            float f[8];
            #pragma unroll
            for (int j = 0; j < 8; ++j)
                f[j] = xb[(size_t)(s*32 + 8*l4 + j) * HWC + su*16 + l15];
            unsigned pk[4];
            #pragma unroll
            for (int d = 0; d < 4; ++d) pk[d] = cvtpk(f[2*d], f[2*d+1]);
            bf16x8 A = __builtin_bit_cast(bf16x8, make_uint4(pk[0], pk[1], pk[2], pk[3]));
            #pragma unroll
            for (int fn = 0; fn < 4; ++fn)
                acc[su][fn] = __builtin_amdgcn_mfma_f32_16x16x32_bf16(A, bw[fn][s], acc[su][fn], 0,0,0);
        }
    }

    unsigned short* sl = slab[wv];
    #pragma unroll
    for (int su = 0; su < 4; ++su)
        #pragma unroll
        for (int fn = 0; fn < 4; ++fn)
            #pragma unroll
            for (int r = 0; r < 4; ++r)
                sl[(su*16 + 4*l4 + r) * 72 + 16*fn + l15] = f2bf(acc[su][fn][r] + pb[fn]);
    const uint4* srow = (const uint4*)(sl + lane * 72);
    uint4* drow = (uint4*)(xp + (size_t)(pxb + lane) * 64);
    #pragma unroll
    for (int q = 0; q < 8; ++q) drow[q] = srow[q];
}

// ---------------- K3: fused, merged lerp||GEMM pipeline ---------------------
// 512 blocks x 512 thr (8 waves, all-identical roles). Block = 2 rows, 256 px.
// LDS = 160 KiB: window 6x128px x128B (XOR-swizzled) + 2x32KB At double buf.
// Step kk: {B-frag loads; lerp(kk)->buf[kk&1]; GEMM(kk-1)<-buf[(kk-1)&1]};
// ONE barrier per step. GEMM's ds_read+MFMA stream is independent in-wave
// work covering the lerp's corner-read latency. 13 barriers total (r7: 22).
__global__ __launch_bounds__(512, 2) void gather_einsum(
        const unsigned short* __restrict__ xp,
        const unsigned short* __restrict__ Wb,
        const unsigned short* __restrict__ Wc,
        const float* __restrict__ off_b,
        const float* __restrict__ mod_b,
        float* __restrict__ out)
{
    __shared__ char smem[163840];
    char* winc = smem;                       // [6][128] px, 128B, swizzled
    float* epi = (float*)smem;               // epilogue [128][260] f32

    const int tid  = (int)threadIdx.x;
    const int lane = tid & 63;
    const int wv   = tid >> 6;       // 0..7
    const int l15  = lane & 15;
    const int l4   = lane >> 4;

    int bid = (int)blockIdx.x;
    int bswz = (bid & 7) * 64 + (bid >> 3);
    const int b  = bswz >> 6;
    const int h0 = (bswz & 63) * 2;

    const unsigned short* xpb = xp + (size_t)b * HWC * CINC;

    // ---- stage window rows h0-2..h0+3, swizzled ----
    #pragma unroll
    for (int i = 0; i < 12; ++i) {
        int c = i * 512 + tid;            // 0..6143
        int r = c >> 10;
        int c10 = c & 1023;
        int xph = c10 >> 3, g = c10 & 7;
        int y = h0 - 2 + r;
        uint4 v = make_uint4(0u,0u,0u,0u);
        if ((unsigned)y < 128u)
            v = *(const uint4*)(xpb + ((size_t)y * 128 + xph) * 64 + g * 8);
        *(uint4*)(winc + (r*128 + xph)*128 + ((g ^ (xph & 7)) << 4)) = v;
    }
    __syncthreads();

    // ---- Phase O: offset/mask conv (all 8 waves, 32 px each) ----
    const int hrow = wv >> 2;
    const int x0w  = (wv & 3) * 32;
    {
        f32x4 aco[2][2];
        #pragma unroll
        for (int j = 0; j < 2; ++j)
            #pragma unroll
            for (int fn = 0; fn < 2; ++fn) aco[j][fn] = (f32x4){0.f,0.f,0.f,0.f};

        #pragma unroll
        for (int kk = 0; kk < 9; ++kk) {
            bf16x8 bc0[2], bc1[2];
            #pragma unroll
            for (int fn = 0; fn < 2; ++fn) {
                bc0[fn] = *(const bf16x8*)(Wc + (size_t)(16*fn + l15) * KDIM + kk*64 + 8*l4);
                bc1[fn] = *(const bf16x8*)(Wc + (size_t)(16*fn + l15) * KDIM + kk*64 + 32 + 8*l4);
            }
            int wr_ = hrow + (kk / 3) + 1;
            #pragma unroll
            for (int j = 0; j < 2; ++j) {
                int xx = x0w + j*16 + l15 + (kk % 3) - 1;
                bool xv = (unsigned)xx < 128u;
                int xc = xx < 0 ? 0 : (xx > 127 ? 127 : xx);
                int sx = xc & 7;
                const char* rr = winc + (wr_*128 + xc)*128;
                uint4 a0 = *(const uint4*)(rr + ((l4 ^ sx) << 4));
                uint4 a1 = *(const uint4*)(rr + (((l4+4) ^ sx) << 4));
                if (!xv) { a0 = make_uint4(0,0,0,0); a1 = make_uint4(0,0,0,0); }
                bf16x8 A0 = __builtin_bit_cast(bf16x8, a0);
                bf16x8 A1 = __builtin_bit_cast(bf16x8, a1);
                #pragma unroll
                for (int fn = 0; fn < 2; ++fn) {
                    aco[j][fn] = __builtin_amdgcn_mfma_f32_16x16x32_bf16(A0, bc0[fn], aco[j][fn], 0,0,0);
                    aco[j][fn] = __builtin_amdgcn_mfma_f32_16x16x32_bf16(A1, bc1[fn], aco[j][fn], 0,0,0);
                }
            }
        }
        // D -> Dt[px][o] (pitch 29 f32) in At area
        float* Dt = (float*)(smem + AT_BASE);
        #pragma unroll
        for (int j = 0; j < 2; ++j)
        #pragma unroll
        for (int fn = 0; fn < 2; ++fn) {
            int o = 16*fn + l15;
            #pragma unroll
            for (int r = 0; r < 4; ++r) {
                int pr = 4*l4 + r;
                int px = wv*32 + j*16 + pr;
                float v = aco[j][fn][r];
                if (o < 18) {
                    v += off_b[o];
                    int k = o >> 1;
                    if ((o & 1) == 0) v += (float)(h0 + hrow - 1 + k/3);
                    else              v += (float)(x0w + j*16 + pr - 1 + (k % 3));
                } else if (o < 27) {
                    v = 2.f / (1.f + __expf(-(v + mod_b[o - 18])));
                }
                if (o < 27) Dt[px*29 + o] = v;
            }
        }
    }
    __syncthreads();

    // ---- Phase C: coords -> regs (this wave's 2 lerp subtiles) ----
    float cy[2][9], cx[2][9], cm[2][9];
    {
        const float* Dt = (const float*)(smem + AT_BASE);
        #pragma unroll
        for (int j = 0; j < 2; ++j) {
            int px = wv*32 + j*16 + l15;
            #pragma unroll
            for (int kk = 0; kk < 9; ++kk) {
                cy[j][kk] = Dt[px*29 + 2*kk];
                cx[j][kk] = Dt[px*29 + 2*kk + 1];
                cm[j][kk] = Dt[px*29 + 18 + kk];
            }
        }
    }
    __syncthreads();   // coords read before lerp overwrites At area

    // ---- main pipelined loop ----
    f32x4 acc[8][2];
    #pragma unroll
    for (int m = 0; m < 8; ++m) { acc[m][0] = (f32x4){0.f,0.f,0.f,0.f};
                                  acc[m][1] = (f32x4){0.f,0.f,0.f,0.f}; }

    const int wr = wv >> 2, wc = wv & 3;
    const unsigned short* wrow = Wb + (size_t)(32*wc + l15) * KDIM + 8*l4;
    const int sw  = l15 & 7;
    const int ao1 = (l4 ^ sw) << 4, ao2 = ((l4 + 4) ^ sw) << 4;

    #define LERP_TILE(kk_)  do {                                              \
        char* Ab = smem + AT_BASE + ((kk_) & 1) * AT_SZ;                      \
        _Pragma("unroll")                                                     \
        for (int j = 0; j < 2; ++j) {                                         \
            float Y = cy[j][kk_], X = cx[j][kk_], M = cm[j][kk_];             \
            float yf = floorf(Y), xf = floorf(X);                             \
            float wy = Y - yf, wx = X - xf;                                   \
            int y0 = (int)yf, x0i = (int)xf;                                  \
            int y1 = y0 + 1, x1 = x0i + 1;                                    \
            bool yv0 = (unsigned)y0 < 128u, yv1 = (unsigned)y1 < 128u;        \
            bool xv0 = (unsigned)x0i < 128u, xv1 = (unsigned)x1 < 128u;       \
            int xc0 = x0i < 0 ? 0 : (x0i > 127 ? 127 : x0i);                  \
            int xc1 = x1  < 0 ? 0 : (x1  > 127 ? 127 : x1);                   \
            int wr0 = y0 - (h0 - 2), wr1 = wr0 + 1;                           \
            int wc0 = wr0 < 0 ? 0 : (wr0 > 5 ? 5 : wr0);                      \
            int wc1 = wr1 < 0 ? 0 : (wr1 > 5 ? 5 : wr1);                      \
            int s0 = xc0 & 7, s1 = xc1 & 7;                                   \
            const char* r00 = winc + (wc0*128 + xc0)*128;                     \
            const char* r01 = winc + (wc0*128 + xc1)*128;                     \
            const char* r10 = winc + (wc1*128 + xc0)*128;                     \
            const char* r11 = winc + (wc1*128 + xc1)*128;                     \
            uint4 cb0 = *(const uint4*)(r00 + ((l4 ^ s0) << 4));              \
            uint4 cb1 = *(const uint4*)(r00 + (((l4+4) ^ s0) << 4));          \
            uint4 cb2 = *(const uint4*)(r01 + ((l4 ^ s1) << 4));              \
            uint4 cb3 = *(const uint4*)(r01 + (((l4+4) ^ s1) << 4));          \
            uint4 cb4 = *(const uint4*)(r10 + ((l4 ^ s0) << 4));              \
            uint4 cb5 = *(const uint4*)(r10 + (((l4+4) ^ s0) << 4));          \
            uint4 cb6 = *(const uint4*)(r11 + ((l4 ^ s1) << 4));              \
            uint4 cb7 = *(const uint4*)(r11 + (((l4+4) ^ s1) << 4));          \
            bool oob = (yv0 && (unsigned)wr0 > 5u) || (yv1 && (unsigned)wr1 > 5u); \
            if (__builtin_expect(oob, 0)) {                                   \
                int yc0 = y0 < 0 ? 0 : (y0 > 127 ? 127 : y0);                 \
                int yc1 = y1 < 0 ? 0 : (y1 > 127 ? 127 : y1);                 \
                const unsigned short* p00 = xpb + (size_t)(yc0*128 + xc0)*64 + 8*l4; \
                const unsigned short* p01 = xpb + (size_t)(yc0*128 + xc1)*64 + 8*l4; \
                const unsigned short* p10 = xpb + (size_t)(yc1*128 + xc0)*64 + 8*l4; \
                const unsigned short* p11 = xpb + (size_t)(yc1*128 + xc1)*64 + 8*l4; \
                cb0 = *(const uint4*)(p00);  cb1 = *(const uint4*)(p00 + 32); \
                cb2 = *(const uint4*)(p01);  cb3 = *(const uint4*)(p01 + 32); \
                cb4 = *(const uint4*)(p10);  cb5 = *(const uint4*)(p10 + 32); \
                cb6 = *(const uint4*)(p11);  cb7 = *(const uint4*)(p11 + 32); \
            }                                                                 \
            float u00 = (1.f - wy) * (1.f - wx) * M * ((yv0 && xv0) ? 1.f : 0.f); \
            float u01 = (1.f - wy) * wx         * M * ((yv0 && xv1) ? 1.f : 0.f); \
            float u10 = wy * (1.f - wx)         * M * ((yv1 && xv0) ? 1.f : 0.f); \
            float u11 = wy * wx                 * M * ((yv1 && xv1) ? 1.f : 0.f); \
            unsigned pk0[4], pk1[4];                                          \
            _Pragma("unroll")                                                 \
            for (int d = 0; d < 4; ++d) {                                     \
                unsigned q00, q01, q10, q11;                                  \
                q00 = cb0[d]; q01 = cb2[d]; q10 = cb4[d]; q11 = cb6[d];       \
                {                                                             \
                    float slo = bf_lo(q00)*u00 + bf_lo(q01)*u01 + bf_lo(q10)*u10 + bf_lo(q11)*u11; \
                    float shi = bf_hi(q00)*u00 + bf_hi(q01)*u01 + bf_hi(q10)*u10 + bf_hi(q11)*u11; \
                    pk0[d] = cvtpk(slo, shi);                                 \
                }                                                             \
                q00 = cb1[d]; q01 = cb3[d]; q10 = cb5[d]; q11 = cb7[d];       \
                {                                                             \
                    float slo = bf_lo(q00)*u00 + bf_lo(q01)*u01 + bf_lo(q10)*u10 + bf_lo(q11)*u11; \
                    float shi = bf_hi(q00)*u00 + bf_hi(q01)*u01 + bf_hi(q10)*u10 + bf_hi(q11)*u11; \
                    pk1[d] = cvtpk(slo, shi);                                 \
                }                                                             \
            }                                                                 \
            int pxl = wv*32 + j*16 + l15;                                     \
            char* ab = Ab + pxl*128;                                          \
            *(uint4*)(ab + ao1) = make_uint4(pk0[0], pk0[1], pk0[2], pk0[3]); \
            *(uint4*)(ab + ao2) = make_uint4(pk1[0], pk1[1], pk1[2], pk1[3]); \
        }                                                                     \
    } while (0)

    #define GEMM_STEP(g_)  do {                                               \
        const char* Ab = smem + AT_BASE + ((g_) & 1) * AT_SZ;                 \
        bf16x8 Bf00 = *(const bf16x8*)(wrow + (g_)*64);                       \
        bf16x8 Bf01 = *(const bf16x8*)(wrow + (g_)*64 + 32);                  \
        bf16x8 Bf10 = *(const bf16x8*)(wrow + (size_t)16*KDIM + (g_)*64);     \
        bf16x8 Bf11 = *(const bf16x8*)(wrow + (size_t)16*KDIM + (g_)*64 + 32);\
        _Pragma("unroll")                                                     \
        for (int m = 0; m < 8; ++m) {                                         \
            const char* ar = Ab + (128*wr + 16*m + l15)*128;                  \
            bf16x8 A0 = *(const bf16x8*)(ar + ao1);                           \
            bf16x8 A1 = *(const bf16x8*)(ar + ao2);                           \
            acc[m][0] = __builtin_amdgcn_mfma_f32_16x16x32_bf16(A0, Bf00, acc[m][0], 0,0,0); \
            acc[m][0] = __builtin_amdgcn_mfma_f32_16x16x32_bf16(A1, Bf01, acc[m][0], 0,0,0); \
            acc[m][1] = __builtin_amdgcn_mfma_f32_16x16x32_bf16(A0, Bf10, acc[m][1], 0,0,0); \
            acc[m][1] = __builtin_amdgcn_mfma_f32_16x16x32_bf16(A1, Bf11, acc[m][1], 0,0,0); \
        }                                                                     \
    } while (0)

    // prologue
    LERP_TILE(0);
    __syncthreads();
    // steady state: lerp(kk) || GEMM(kk-1), one barrier per step
    #pragma unroll 1
    for (int kk = 1; kk < 9; ++kk) {
        LERP_TILE(kk);
        GEMM_STEP(kk - 1);
        __syncthreads();
    }
    // epilogue step
    GEMM_STEP(8);
    __syncthreads();

    #undef LERP_TILE
    #undef GEMM_STEP

    // ---- epilogue: acc -> LDS [cout][px pitch 260] -> full-line stores ----
    #pragma unroll
    for (int m = 0; m < 8; ++m)
        #pragma unroll
        for (int f = 0; f < 2; ++f)
            *(f32x4*)(epi + (size_t)(32*wc + 16*f + l15) * 260 + 128*wr + 16*m + 4*l4) = acc[m][f];
    __syncthreads();

    float* ob = out + (size_t)b * COUTC * HWC + h0 * 128;
    #pragma unroll
    for (int it = 0; it < 16; ++it) {
        int idx = it * 512 + tid;
        int o = idx >> 6, c = idx & 63;
        f32x4 v = *(const f32x4*)(epi + (size_t)o * 260 + 4*c);
        *(f32x4*)(ob + (size_t)o * HWC + 4*c) = v;
    }
}

extern "C" void kernel_launch(void* const* d_in, const int* in_sizes, int n_in,
                              void* d_out, int out_size, void* d_ws, size_t ws_size,
                              hipStream_t stream)
{
    const float* x     = (const float*)d_in[0];
    const float* pre_w = (const float*)d_in[1];
    const float* pre_b = (const float*)d_in[2];
    const float* off_w = (const float*)d_in[3];
    const float* off_b = (const float*)d_in[4];
    const float* mod_w = (const float*)d_in[5];
    const float* mod_b = (const float*)d_in[6];
    const float* reg_w = (const float*)d_in[7];
    float* out = (float*)d_out;

    unsigned short* xp = (unsigned short*)d_ws;                              // 16,777,216 B
    unsigned short* Wb = (unsigned short*)((char*)d_ws + 16777216);          //    147,456 B
    unsigned short* Wc = (unsigned short*)((char*)d_ws + 16924672);          //     36,864 B
    unsigned short* Wp = (unsigned short*)((char*)d_ws + 16961536);          //      8,192 B

    prep_weights<<<dim3(376), dim3(256), 0, stream>>>(off_w, mod_w, reg_w, pre_w, Wb, Wc, Wp);
    conv1x1     <<<dim3(512), dim3(256), 0, stream>>>(x, Wp, pre_b, xp);
    gather_einsum<<<dim3(512), dim3(512), 0, stream>>>(xp, Wb, Wc, off_b, mod_b, out);
}